// Round 3
// baseline (329.912 us; speedup 1.0000x reference)
//
#include <hip/hip_runtime.h>
#include <hip/hip_bf16.h>

// Transposed conv (full conv): out[b,p,q,co] = sum_{kh,kw,ci} in[b,p-kh,q-kw,ci]*K[ci,co,kh,kw]
// B=8 H=W=256 C=64, out 8x258x258x64 fp32. bf16 MFMA path.
//
// R2: R1 + memory-level parallelism. Staging fully unrolled & branch-free
// (clamped addresses, all 20 dwordx4 loads in flight, select-zero after),
// tap loop fully unrolled so B-frag L2 loads + A ds_reads pipeline across taps.

#define OH 258
#define OW 258

typedef __bf16 bf16x8 __attribute__((ext_vector_type(8)));
typedef float  f32x4  __attribute__((ext_vector_type(4)));

// ws layout: wsW[((tap*2+s)*64+co)*32 + c] = K[ci=32s+c][co][kh][kw], tap=kh*3+kw
__global__ void prep_w_kernel(const float* __restrict__ k, __bf16* __restrict__ wsW) {
    int i = blockIdx.x * 256 + threadIdx.x;            // [0, 36864)
    int c  = i & 31;
    int co = (i >> 5) & 63;
    int st = i >> 11;                                  // [0,18)
    int s   = st & 1;
    int tap = st >> 1;
    int kh = tap / 3, kw = tap % 3;
    float v = k[(s * 32 + c) * 576 + co * 9 + kh * 3 + kw];
    wsW[i] = (__bf16)v;
}

__global__ __launch_bounds__(512, 4)
void tconv_kernel(const float* __restrict__ in, const __bf16* __restrict__ wsW,
                  float* __restrict__ out) {
    // input patch [pix=34*18][64ci] bf16, 16B granules XOR-swizzled by pix&7
    __shared__ __bf16 lds_in[612 * 64];   // 78336 B -> 2 blocks/CU

    const int tid = threadIdx.x;
    const int b  = blockIdx.z;
    const int p0 = blockIdx.y * 32;
    const int q0 = blockIdx.x * 16;

    // ---- stage input patch rows p0-2..p0+31, cols q0-2..q0+15; zero-pad OOB.
    // Phase 1: issue ALL loads (clamped addresses, unconditional) -> max MLP.
    f32x4 va[10], vb[10];
    #pragma unroll
    for (int k = 0; k < 10; ++k) {
        int it = tid + k * 512;                        // < 5120; valid if < 4896
        int pix = it >> 3, c8 = it & 7;
        int r = pix / 18, c = pix - r * 18;
        int ip = p0 - 2 + r, iq = q0 - 2 + c;
        bool inb = ((unsigned)ip < 256u) & ((unsigned)iq < 256u) & (it < 4896);
        int ipc = inb ? ip : 0;
        int iqc = inb ? iq : 0;
        const float* g = in + (((size_t)b * 256 + ipc) * 256 + iqc) * 64 + c8 * 8;
        va[k] = *(const f32x4*)g;
        vb[k] = *(const f32x4*)(g + 4);
    }
    // Phase 2: convert, zero OOB, write LDS.
    #pragma unroll
    for (int k = 0; k < 10; ++k) {
        int it = tid + k * 512;
        int pix = it >> 3, c8 = it & 7;
        int r = pix / 18, c = pix - r * 18;
        int ip = p0 - 2 + r, iq = q0 - 2 + c;
        bool inb = ((unsigned)ip < 256u) & ((unsigned)iq < 256u);
        bf16x8 w;
        #pragma unroll
        for (int e = 0; e < 4; ++e) {
            float f0 = inb ? va[k][e] : 0.f;
            float f1 = inb ? vb[k][e] : 0.f;
            w[e]     = (__bf16)f0;
            w[e + 4] = (__bf16)f1;
        }
        if (it < 4896)
            *(bf16x8*)&lds_in[pix * 64 + ((c8 ^ (pix & 7)) * 8)] = w;
    }
    __syncthreads();   // the ONLY barrier

    const int wv = tid >> 6, lane = tid & 63;
    const int ml = lane & 15, h = lane >> 4;           // A: m=ml; B: n=ml; k-quad=h
    const int woff = ml * 32 + h * 8;                  // B-frag lane offset (elems)

    f32x4 acc[4][4] = {};   // mt = output row within wave's 4; nt = co/16

    #pragma unroll
    for (int tap = 0; tap < 9; ++tap) {
        const int kh = tap / 3, kw = tap - kh * 3;
        const __bf16* wt = wsW + tap * 4096;
        #pragma unroll
        for (int s = 0; s < 2; ++s) {
            bf16x8 bfr[4];
            #pragma unroll
            for (int nt = 0; nt < 4; ++nt)
                bfr[nt] = *(const bf16x8*)(wt + s * 2048 + nt * 512 + woff);
            const int j = s * 4 + h;                   // 16B granule index within pixel
            #pragma unroll
            for (int mt = 0; mt < 4; ++mt) {
                int row = wv * 4 + mt + 2 - kh;        // patch row
                int pix = row * 18 + (2 - kw) + ml;    // m-tile = one output row (16 q)
                bf16x8 afr = *(const bf16x8*)&lds_in[pix * 64 + ((j ^ (pix & 7)) * 8)];
                #pragma unroll
                for (int nt = 0; nt < 4; ++nt)
                    acc[mt][nt] = __builtin_amdgcn_mfma_f32_16x16x32_bf16(
                        afr, bfr[nt], acc[mt][nt], 0, 0, 0);
            }
        }
    }

    // ---- epilogue: D layout col(co)=ml, row(q within row-tile)=h*4+reg
    #pragma unroll
    for (int mt = 0; mt < 4; ++mt) {
        int p = p0 + wv * 4 + mt;
        if (p < OH) {
            int qb = q0 + h * 4;
            #pragma unroll
            for (int nt = 0; nt < 4; ++nt) {
                float* op = out + (((size_t)b * OH + p) * OW + qb) * 64 + nt * 16 + ml;
                #pragma unroll
                for (int r = 0; r < 4; ++r)
                    if (qb + r < OW) op[(size_t)r * 64] = acc[mt][nt][r];
            }
        }
    }
}

extern "C" void kernel_launch(void* const* d_in, const int* in_sizes, int n_in,
                              void* d_out, int out_size, void* d_ws, size_t ws_size,
                              hipStream_t stream) {
    (void)in_sizes; (void)n_in; (void)out_size; (void)ws_size;
    const float* in   = (const float*)d_in[0];
    const float* kern = (const float*)d_in[1];
    float* out = (float*)d_out;
    __bf16* wsW = (__bf16*)d_ws;   // 36864 bf16 = 73728 B

    prep_w_kernel<<<144, 256, 0, stream>>>(kern, wsW);
    dim3 grid(17, 9, 8);           // q-tiles, p-tiles, batch
    tconv_kernel<<<grid, 512, 0, stream>>>(in, wsW, out);
}